// Round 11
// baseline (371.285 us; speedup 1.0000x reference)
//
#include <hip/hip_runtime.h>
#include <math.h>

// AutoCorrelation (Autoformer eval path), MI355X.
// B=8, L=4096, H=8, E=64 -> 512 channels; top_k = int(log(4096)) = 8.
// Round 9 (second resubmit; two GPU-acquisition timeouts, no data):
// k_fft_corr restructured — register-direct coalesced loads of the channel
// series (no LDS staging buffer, no global_load_lds), register prefetch of
// the next channel issued under stages 1-2, all barriers pure lgkmcnt (no
// vmcnt drain anywhere in the loop), CPB=4 + 34.8 KB LDS so 3-4 blocks/CU
// can be resident (was 2).
//   k_transpose: z[b][ch][t] = q[b][t][ch] + i*k[b][t][ch]   (LDS tile xpose)
//   k_fft_corr : per-channel 4096-pt radix-16 FFT of z, cross-spectrum
//                summed over channels into Sf[b][f] (atomic fp32)
//   k_ifft_topk: R = Re(FFT(conj(Sf)))/(L*CH); top-8 + softmax -> w,idx
//   k_gather   : out[b,t,:] = sum_i w_i * v[b,(t+idx_i)%L,:]  (float4)

namespace {
constexpr int LEN  = 4096;
constexpr int NCH  = 512;          // H*E
constexpr int NB   = 8;            // batch
constexpr int KTOP = 8;            // int(1.0 * log(4096))
constexpr int TPB  = 256;
constexpr int CPB  = 4;            // channels per block (kernel 1)
constexpr int GPB  = NCH / CPB;    // 128 groups per batch -> 1024 blocks
constexpr size_t SF_BYTES = (size_t)NB * LEN * 2 * sizeof(float); // 262144
constexpr size_t WI_BYTES = (size_t)NB * KTOP * sizeof(float);    // 256
constexpr size_t ZT_OFF   = SF_BYTES + 2 * WI_BYTES;              // 262656
constexpr size_t ZT_BYTES = (size_t)NB * NCH * LEN * 2 * sizeof(float); // 134MB
constexpr int PADN = LEN + (LEN >> 4);  // 4352 float2 = 34816 B
}

#define PD(i) ((i) + ((i) >> 4))

__device__ __forceinline__ float2 cmul(float2 a, float2 b) {
  return make_float2(a.x * b.x - a.y * b.y, a.x * b.y + a.y * b.x);
}

// lgkmcnt-only barrier: orders LDS ops across waves without draining the
// global-load (vmcnt) queue -> register prefetch stays in flight.
#define LGKM_BAR()                                          \
  do {                                                      \
    asm volatile("s_waitcnt lgkmcnt(0)" ::: "memory");      \
    __builtin_amdgcn_s_barrier();                           \
  } while (0)

// Forward 16-point DFT (natural order), 4x4 Cooley-Tukey, all in registers.
__device__ __forceinline__ void dft16(const float2* __restrict__ a,
                                      float2* __restrict__ b) {
  const float C1 = 0.92387953251128674f;   // cos(pi/8)
  const float S1 = 0.38268343236508978f;   // sin(pi/8)
  const float R2 = 0.70710678118654752f;   // sqrt(2)/2
  float2 c[4][4];
  #pragma unroll
  for (int r0 = 0; r0 < 4; ++r0) {
    const float2 x0 = a[r0], x1 = a[4 + r0], x2 = a[8 + r0], x3 = a[12 + r0];
    const float2 s02 = make_float2(x0.x + x2.x, x0.y + x2.y);
    const float2 d02 = make_float2(x0.x - x2.x, x0.y - x2.y);
    const float2 s13 = make_float2(x1.x + x3.x, x1.y + x3.y);
    const float2 d13 = make_float2(x1.x - x3.x, x1.y - x3.y);
    c[r0][0] = make_float2(s02.x + s13.x, s02.y + s13.y);
    c[r0][2] = make_float2(s02.x - s13.x, s02.y - s13.y);
    c[r0][1] = make_float2(d02.x + d13.y, d02.y - d13.x);   // d02 - i*d13
    c[r0][3] = make_float2(d02.x - d13.y, d02.y + d13.x);   // d02 + i*d13
  }
  #pragma unroll
  for (int k0 = 0; k0 < 4; ++k0) {
    float2 t0 = c[0][k0], t1 = c[1][k0], t2 = c[2][k0], t3 = c[3][k0];
    if (k0 == 1) {
      t1 = cmul(t1, make_float2(C1, -S1));
      t2 = cmul(t2, make_float2(R2, -R2));
      t3 = cmul(t3, make_float2(S1, -C1));
    } else if (k0 == 2) {
      t1 = cmul(t1, make_float2(R2, -R2));
      t2 = make_float2(t2.y, -t2.x);                        // * -i
      t3 = cmul(t3, make_float2(-R2, -R2));
    } else if (k0 == 3) {
      t1 = cmul(t1, make_float2(S1, -C1));
      t2 = cmul(t2, make_float2(-R2, -R2));
      t3 = cmul(t3, make_float2(-C1, S1));
    }
    const float2 s02 = make_float2(t0.x + t2.x, t0.y + t2.y);
    const float2 d02 = make_float2(t0.x - t2.x, t0.y - t2.y);
    const float2 s13 = make_float2(t1.x + t3.x, t1.y + t3.y);
    const float2 d13 = make_float2(t1.x - t3.x, t1.y - t3.y);
    b[k0]      = make_float2(s02.x + s13.x, s02.y + s13.y);
    b[k0 + 8]  = make_float2(s02.x - s13.x, s02.y - s13.y);
    b[k0 + 4]  = make_float2(d02.x + d13.y, d02.y - d13.x);
    b[k0 + 12] = make_float2(d02.x - d13.y, d02.y + d13.x);
  }
}

// In-place radix-16 Stockham DIF, N=4096=16^3 (standard __syncthreads
// version; used by k_ifft_topk and the strided fallback).
__device__ __forceinline__ void fft4096_ip(float2* __restrict__ buf, int tid)
{
  float2 a[16], b[16];
  const float NEG2PI_N = -6.283185307179586f / 4096.0f;
  {
    #pragma unroll
    for (int r = 0; r < 16; ++r) a[r] = buf[PD(tid + 256 * r)];
    dft16(a, b);
    float sn, cs;
    __sincosf((float)tid * NEG2PI_N, &sn, &cs);
    const float2 w1 = make_float2(cs, sn);
    __syncthreads();
    float2 w = make_float2(1.f, 0.f);
    #pragma unroll
    for (int k = 0; k < 16; ++k) {
      buf[PD(16 * tid + k)] = cmul(b[k], w);
      w = cmul(w, w1);
    }
  }
  __syncthreads();
  {
    const int q = tid & 15, p = tid >> 4;
    #pragma unroll
    for (int r = 0; r < 16; ++r) a[r] = buf[PD(tid + 256 * r)];
    dft16(a, b);
    float sn, cs;
    __sincosf((float)(16 * p) * NEG2PI_N, &sn, &cs);
    const float2 w1 = make_float2(cs, sn);
    __syncthreads();
    float2 w = make_float2(1.f, 0.f);
    const int ob = q + 256 * p;
    #pragma unroll
    for (int k = 0; k < 16; ++k) {
      buf[PD(ob + 16 * k)] = cmul(b[k], w);
      w = cmul(w, w1);
    }
  }
  __syncthreads();
  {
    #pragma unroll
    for (int r = 0; r < 16; ++r) a[r] = buf[PD(tid + 256 * r)];
    dft16(a, b);
    __syncthreads();
    #pragma unroll
    for (int k = 0; k < 16; ++k) buf[PD(tid + 256 * k)] = b[k];
  }
  __syncthreads();
}

// ---------------------------------------------------------------------------
// Packed transpose: zt[b][c][t] = (q[b][t][c], k[b][t][c]).
__global__ __launch_bounds__(TPB) void k_transpose(
    const float* __restrict__ qg, const float* __restrict__ kg,
    float2* __restrict__ zt)
{
  __shared__ float2 tile[64 * 65];
  const int bt  = blockIdx.x;               // [B][L/64][CH/64]
  const int b   = bt >> 9;
  const int t0  = ((bt >> 3) & 63) * 64;
  const int c0  = (bt & 7) * 64;
  const int tid = threadIdx.x;
  const size_t base = (size_t)b * LEN * NCH;

  #pragma unroll
  for (int r = 0; r < 16; ++r) {
    const int idx  = r * TPB + tid;
    const int ch_l = idx & 63;
    const int t_l  = idx >> 6;
    const size_t g = base + (size_t)(t0 + t_l) * NCH + (c0 + ch_l);
    tile[t_l * 65 + ch_l] = make_float2(qg[g], kg[g]);
  }
  __syncthreads();
  #pragma unroll
  for (int r = 0; r < 16; ++r) {
    const int idx  = r * TPB + tid;
    const int t_l  = idx & 63;
    const int ch_l = idx >> 6;
    zt[((size_t)b * NCH + (c0 + ch_l)) * LEN + (t0 + t_l)] =
        tile[t_l * 65 + ch_l];
  }
}

// ---------------------------------------------------------------------------
// P[f] = Qf*conj(Kf) = (i/4)*(A+B)*conj(A-B), A=Z[f], B=conj(Z[(N-f)%N]).
__device__ __forceinline__ void spec_acc(const float2* __restrict__ buf,
                                         int tid, float2* __restrict__ acc)
{
  #pragma unroll
  for (int r = 0; r < 16; ++r) {
    const int f = tid + 256 * r;
    const float2 A = buf[PD(f)];
    float2 Bv = buf[PD((LEN - f) & (LEN - 1))];
    Bv.y = -Bv.y;
    const float Sx = A.x + Bv.x, Sy = A.y + Bv.y;
    const float Dx = A.x - Bv.x, Dy = -(A.y - Bv.y);
    const float Mx = Sx * Dx - Sy * Dy;
    const float My = Sx * Dy + Sy * Dx;
    acc[r].x += -0.25f * My;
    acc[r].y +=  0.25f * Mx;
  }
}

// Register-direct pipelined FFT+cross-spectrum:
//  - stage-0 input loaded straight into registers (coalesced float2), no
//    staging LDS, no B1 barrier;
//  - next channel's loads issued right after dft16 frees the registers,
//    pinned before the following "memory" asm barrier (can't sink); the
//    compiler's own vmcnt wait lands at next loop-top use -> latency hidden
//    per-wave, and NO barrier in the loop drains vmcnt;
//  - LDS = bufA only (34.8 KB) -> up to 4 blocks/CU; CPB=4 doubles the grid
//    so the extra residency is actually used.
__global__ __launch_bounds__(TPB) void k_fft_corr(
    const float2* __restrict__ zt,          // [NB][NCH][LEN]
    float* __restrict__ Sf)                 // [NB][LEN][2]
{
  __shared__ float2 bufA[PADN];             // padded FFT workspace
  const int tid = threadIdx.x;
  const int b   = blockIdx.x / GPB;
  const int g   = blockIdx.x % GPB;
  const float2* base = zt + ((size_t)b * NCH + g * CPB) * LEN;

  float2 acc[16];
  #pragma unroll
  for (int r = 0; r < 16; ++r) acc[r] = make_float2(0.f, 0.f);

  const float NEG2PI_N = -6.283185307179586f / 4096.0f;

  // prologue: issue channel-0 loads (coalesced, per-lane registers)
  float2 a[16];
  #pragma unroll
  for (int r = 0; r < 16; ++r) a[r] = base[tid + 256 * r];

  for (int cc = 0; cc < CPB; ++cc) {
    float2 bb[16], t16[16];
    float sn, cs;
    // ---- stage 0: registers -> dft16 (vmcnt wait auto-inserted here) ----
    dft16(a, bb);
    __sincosf((float)tid * NEG2PI_N, &sn, &cs);
    {
      const float2 w1 = make_float2(cs, sn);
      float2 w = make_float2(1.f, 0.f);
      #pragma unroll
      for (int k = 0; k < 16; ++k) {        // PD(16*tid+k) == 17*tid+k
        bufA[PD(16 * tid + k)] = cmul(bb[k], w);
        w = cmul(w, w1);
      }
    }
    // prefetch next channel into the now-free registers (issued before the
    // barrier asm; stays in flight through stages 1-2 + spec)
    if (cc + 1 < CPB) {
      const float2* nsrc = base + (size_t)(cc + 1) * LEN;
      #pragma unroll
      for (int r = 0; r < 16; ++r) a[r] = nsrc[tid + 256 * r];
    }
    LGKM_BAR();                             // B2: stage-0 writes visible
    // ---- stage 1 ----
    #pragma unroll
    for (int r = 0; r < 16; ++r) t16[r] = bufA[PD(tid + 256 * r)];
    LGKM_BAR();                             // B3: reads done before writes
    dft16(t16, bb);
    __sincosf((float)(16 * (tid >> 4)) * NEG2PI_N, &sn, &cs);
    {
      const float2 w1 = make_float2(cs, sn);
      float2 w = make_float2(1.f, 0.f);
      const int ob = (tid & 15) + 256 * (tid >> 4);
      #pragma unroll
      for (int k = 0; k < 16; ++k) {
        bufA[PD(ob + 16 * k)] = cmul(bb[k], w);
        w = cmul(w, w1);
      }
    }
    LGKM_BAR();                             // B4
    // ---- stage 2 (p=0 -> no twiddles) ----
    #pragma unroll
    for (int r = 0; r < 16; ++r) t16[r] = bufA[PD(tid + 256 * r)];
    LGKM_BAR();                             // B5
    dft16(t16, bb);
    #pragma unroll
    for (int k = 0; k < 16; ++k) bufA[PD(tid + 256 * k)] = bb[k];
    LGKM_BAR();                             // B6: writes visible for spec
    spec_acc(bufA, tid, acc);
    LGKM_BAR();                             // B7: spec reads done
  }
  float* dstp = Sf + (size_t)b * LEN * 2;
  #pragma unroll
  for (int r = 0; r < 16; ++r) {
    const int f = tid + 256 * r;
    atomicAdd(&dstp[2 * f],     acc[r].x);
    atomicAdd(&dstp[2 * f + 1], acc[r].y);
  }
}

// Fallback (ws too small for transposed copy): strided loads from q,k.
__global__ __launch_bounds__(TPB) void k_fft_corr_strided(
    const float* __restrict__ qg, const float* __restrict__ kg,
    float* __restrict__ Sf)
{
  __shared__ float2 buf[PADN];
  const int tid = threadIdx.x;
  const int b   = blockIdx.x / GPB;
  const int g   = blockIdx.x % GPB;
  const int ch0 = g * CPB;

  float2 acc[16];
  #pragma unroll
  for (int r = 0; r < 16; ++r) acc[r] = make_float2(0.f, 0.f);

  const size_t base = (size_t)b * LEN * NCH;
  for (int cc = 0; cc < CPB; ++cc) {
    const int ch = ch0 + cc;
    #pragma unroll
    for (int r = 0; r < 16; ++r) {
      const int t = tid + 256 * r;
      const size_t idx = base + (size_t)t * NCH + ch;
      buf[PD(t)] = make_float2(qg[idx], kg[idx]);
    }
    __syncthreads();
    fft4096_ip(buf, tid);
    spec_acc(buf, tid, acc);
    __syncthreads();
  }
  float* dstp = Sf + (size_t)b * LEN * 2;
  #pragma unroll
  for (int r = 0; r < 16; ++r) {
    const int f = tid + 256 * r;
    atomicAdd(&dstp[2 * f],     acc[r].x);
    atomicAdd(&dstp[2 * f + 1], acc[r].y);
  }
}

// ---------------------------------------------------------------------------
__global__ __launch_bounds__(TPB) void k_ifft_topk(
    const float* __restrict__ Sf,           // [NB][LEN][2]
    float* __restrict__ wout, int* __restrict__ iout)
{
  __shared__ float2 buf[PADN];
  __shared__ float swv[4];
  __shared__ int   swi[4];
  __shared__ int   gsel;
  __shared__ float topv[KTOP];
  __shared__ int   topi[KTOP];
  const int tid = threadIdx.x;
  const int b   = blockIdx.x;

  const float2* srcp = (const float2*)Sf + (size_t)b * LEN;
  #pragma unroll
  for (int r = 0; r < 16; ++r) {
    const int f = tid + 256 * r;
    const float2 s = srcp[f];
    buf[PD(f)] = make_float2(s.x, -s.y);    // conj(P)
  }
  __syncthreads();
  fft4096_ip(buf, tid);

  const float scale = 1.0f / (4096.0f * 512.0f);
  float rv[16];
  #pragma unroll
  for (int r = 0; r < 16; ++r) rv[r] = buf[PD(tid + 256 * r)].x * scale;

  const int lane = tid & 63, wv = tid >> 6;
  for (int it = 0; it < KTOP; ++it) {
    float best = -INFINITY;
    int   bi   = 0x7fffffff;
    #pragma unroll
    for (int r = 0; r < 16; ++r) {
      if (rv[r] > best) { best = rv[r]; bi = tid + 256 * r; }
    }
    #pragma unroll
    for (int off = 32; off > 0; off >>= 1) {
      const float ov = __shfl_xor(best, off);
      const int   oi = __shfl_xor(bi, off);
      if (ov > best || (ov == best && oi < bi)) { best = ov; bi = oi; }
    }
    if (lane == 0) { swv[wv] = best; swi[wv] = bi; }
    __syncthreads();
    if (tid == 0) {
      float gv = swv[0]; int gi = swi[0];
      for (int w2 = 1; w2 < 4; ++w2)
        if (swv[w2] > gv || (swv[w2] == gv && swi[w2] < gi)) {
          gv = swv[w2]; gi = swi[w2];
        }
      topv[it] = gv; topi[it] = gi; gsel = gi;
    }
    __syncthreads();
    const int gi = gsel;
    if ((gi & 255) == tid) {
      const int rr = gi >> 8;
      #pragma unroll
      for (int r = 0; r < 16; ++r)          // static idx (avoid scratch)
        if (r == rr) rv[r] = -INFINITY;
    }
  }
  if (tid == 0) {
    const float m = topv[0];
    float e[KTOP], den = 0.f;
    #pragma unroll
    for (int i = 0; i < KTOP; ++i) { e[i] = expf(topv[i] - m); den += e[i]; }
    #pragma unroll
    for (int i = 0; i < KTOP; ++i) {
      wout[b * KTOP + i] = e[i] / den;
      iout[b * KTOP + i] = topi[i];
    }
  }
}

// ---------------------------------------------------------------------------
// XCD-batch swizzle: batch = blockIdx & 7 pins each batch's v-slab to one
// XCD's L2 (round-robin dispatch maps blockIdx%8 -> XCD).
__global__ __launch_bounds__(256) void k_gather(
    const float4* __restrict__ v, const float* __restrict__ wk,
    const int* __restrict__ ik, float4* __restrict__ out)
{
  __shared__ float sw[KTOP];
  __shared__ int   sidx[KTOP];
  const int b  = blockIdx.x & 7;            // batch == XCD
  const int tp = blockIdx.x >> 3;           // [0,2048)
  if (threadIdx.x < KTOP) {
    sw[threadIdx.x]   = wk[b * KTOP + threadIdx.x];
    sidx[threadIdx.x] = ik[b * KTOP + threadIdx.x];
  }
  __syncthreads();
  const int t = tp * 2 + (threadIdx.x >> 7); // 2 rows / block
  const int c = threadIdx.x & 127;           // float4 lane in 512-f row
  const size_t vbase = (size_t)b * LEN * 128;
  float4 acc = make_float4(0.f, 0.f, 0.f, 0.f);
  #pragma unroll
  for (int i = 0; i < KTOP; ++i) {
    const int st = (t + sidx[i]) & (LEN - 1);
    const float4 x = v[vbase + (size_t)st * 128 + c];
    acc.x += sw[i] * x.x; acc.y += sw[i] * x.y;
    acc.z += sw[i] * x.z; acc.w += sw[i] * x.w;
  }
  out[vbase + (size_t)t * 128 + c] = acc;
}

// ---------------------------------------------------------------------------
extern "C" void kernel_launch(void* const* d_in, const int* in_sizes, int n_in,
                              void* d_out, int out_size, void* d_ws, size_t ws_size,
                              hipStream_t stream) {
  const float* q = (const float*)d_in[0];
  const float* k = (const float*)d_in[1];
  const float* v = (const float*)d_in[2];

  float*  Sf = (float*)d_ws;                               // 262144 B
  float*  wk = (float*)((char*)d_ws + SF_BYTES);
  int*    ik = (int*)((char*)d_ws + SF_BYTES + WI_BYTES);
  float2* zt = (float2*)((char*)d_ws + ZT_OFF);            // 134 MB

  hipMemsetAsync(d_ws, 0, SF_BYTES, stream);
  if (ws_size >= ZT_OFF + ZT_BYTES) {
    k_transpose<<<NB * 64 * 8, TPB, 0, stream>>>(q, k, zt);
    k_fft_corr<<<NB * GPB, TPB, 0, stream>>>(zt, Sf);
  } else {
    k_fft_corr_strided<<<NB * GPB, TPB, 0, stream>>>(q, k, Sf);
  }
  k_ifft_topk<<<NB, TPB, 0, stream>>>(Sf, wk, ik);
  k_gather<<<NB * 2048, 256, 0, stream>>>((const float4*)v, wk, ik,
                                          (float4*)d_out);
}